// Round 5
// baseline (1429.554 us; speedup 1.0000x reference)
//
#include <hip/hip_runtime.h>
#include <hip/hip_bf16.h>
#include <cstddef>

// Problem constants (fixed by setup_inputs)
#define T_TOK 512
#define NH    12
#define HD    64
#define NV    32000
#define CEMB  768
#define NC    50          // vocab chunks
#define VC    (NV/NC)     // 640 rows per chunk
#define NSUB  (VC/64)     // 10 subtiles of 64 rows
#define LOG2E 1.44269504088896340736f

typedef short v8bf __attribute__((ext_vector_type(8)));   // 8 bf16 = 4 VGPRs
typedef float v4f  __attribute__((ext_vector_type(4)));   // MFMA C/D

__device__ __forceinline__ unsigned short f2bf(float f) {  // RNE (cold paths only)
    unsigned u = __float_as_uint(f);
    u += 0x7fffu + ((u >> 16) & 1u);
    return (unsigned short)(u >> 16);
}
// truncate-pack two floats to bf16 pair in one v_perm_b32 (hot loop)
__device__ __forceinline__ unsigned pk_trunc(float hi, float lo) {
    return __builtin_amdgcn_perm(__float_as_uint(hi), __float_as_uint(lo), 0x07060302u);
}
__device__ __forceinline__ unsigned short hi16(float f) {
    return (unsigned short)(__float_as_uint(f) >> 16);
}
__device__ __forceinline__ float bf2f(unsigned short u) {
    return __uint_as_float(((unsigned)u) << 16);
}

// ---------------------------------------------------------------------------
// Kernel 1: Qb[h][t][d] (bf16) = (x . W_ffn^T + b) * LOG2E / tau   (fp32 math)
// ---------------------------------------------------------------------------
__global__ __launch_bounds__(256) void ffn_kernel(
        const float* __restrict__ x, const float* __restrict__ Wf,
        const float* __restrict__ bfv, const float* __restrict__ temps,
        unsigned short* __restrict__ Qb) {
    const int t0 = blockIdx.x * 16, h = blockIdx.y, tid = threadIdx.x;
    __shared__ float xs[16 * 64];
    {   // stage 16 token rows of this head's slice
        int r = tid >> 4, c4 = tid & 15;
        *(float4*)&xs[r*64 + c4*4] =
            *(const float4*)&x[(size_t)(t0 + r)*CEMB + h*HD + c4*4];
    }
    __syncthreads();
    const int e = tid & 63, tq = tid >> 6;           // 4 tokens per thread
    const float4* wrow = (const float4*)(Wf + (size_t)(h*HD + e)*HD);
    float tau = temps[h]; tau = (tau < 0.1f) ? 0.1f : tau;
    const float scale = LOG2E / tau;
    const float b = bfv[h*HD + e];
    float acc[4] = {b, b, b, b};
    const float4* xs4 = (const float4*)xs;
    #pragma unroll
    for (int i = 0; i < 16; ++i) {
        float4 wv = wrow[i];
        #pragma unroll
        for (int k = 0; k < 4; ++k) {
            float4 xv = xs4[(tq*4 + k)*16 + i];      // broadcast within wave
            acc[k] += wv.x*xv.x + wv.y*xv.y + wv.z*xv.z + wv.w*xv.w;
        }
    }
    #pragma unroll
    for (int k = 0; k < 4; ++k)
        Qb[((size_t)h*T_TOK + t0 + tq*4 + k)*HD + e] = f2bf(acc[k]*scale);
}

// ---------------------------------------------------------------------------
// Kernel 2: MFMA flash. Grid (NC, NH), block 512 = 8 waves; wave owns 64 q.
// LDS tiles (bf16, row 128B, granule-XOR swizzle: 16B-octet g of row r lives
// at g^(r&7)):  KB [v][d]  (A-op for S^T=K.Q^T),  ED [d][v]  (B-op for O=P.E),
// PS [q][v] per-wave (A-op for phase B).  Single barrier per subtile, dbuf.
// All hot-loop bf16 conversion is truncation (1 v_perm per pair).
// ---------------------------------------------------------------------------
__global__ __launch_bounds__(512, 6) void flash_mfma(
        const unsigned short* __restrict__ Qb, const float* __restrict__ Wv,
        const float* __restrict__ E, unsigned short* __restrict__ Npart,
        float* __restrict__ Zpart) {
    const int c = blockIdx.x, h = blockIdx.y;
    const int tid  = threadIdx.x;
    const int wq   = tid >> 6;                 // wave id 0..7
    const int l    = tid & 63;
    const int l15  = l & 15, quad = l >> 4;
    const int X7   = l15 & 7;
    const int g0   = (quad ^ X7) * 8;          // octet offsets for b128 frags
    const int g1   = ((4 + quad) ^ X7) * 8;
    const int rowb = l15 * 64;

    __shared__ unsigned short KB[2][4096];     // K subtile  [v][d]
    __shared__ unsigned short ED[2][4096];     // E^T subtile [d][v]
    __shared__ unsigned short PSa[8][1024];    // P per wave: 16 q-rows x 64 v
    unsigned short* PS = &PSa[wq][0];

    const int tbase = wq * 64;                 // this wave's first query

    // ---- Q fragments (B-op): lane holds Q[q=nt*16+l15][d=kb*32+quad*8..+7]
    v8bf qf[4][2];
    #pragma unroll
    for (int nt = 0; nt < 4; ++nt)
        #pragma unroll
        for (int kb = 0; kb < 2; ++kb)
            qf[nt][kb] = *(const v8bf*)&Qb[((size_t)h*T_TOK + tbase + nt*16 + l15)*HD
                                           + kb*32 + quad*8];

    v4f o[4][4];                               // o[nt(q-16)][nd(d-16)]
    #pragma unroll
    for (int a = 0; a < 4; ++a)
        #pragma unroll
        for (int b = 0; b < 4; ++b) { v4f z = {0.f,0.f,0.f,0.f}; o[a][b] = z; }
    float zacc[4] = {0.f, 0.f, 0.f, 0.f};

    // ---- staging addressing (loop-invariant) ----
    // K: lane -> (row kRow, octet kCol8); one b128 LDS write per subtile
    const int kRow = wq*8 + (l >> 3), kCol8 = l & 7;
    const float* kgl = Wv + ((size_t)h*NV + (size_t)c*VC + kRow)*HD + kCol8*8;
    const int kwidx = kRow*64 + ((kCol8 ^ (kRow & 7)) * 8);
    // E: lane -> v-row = l, d-slice = wq*8..+8; 8 scalar b16 writes per subtile
    const float* egl = E + ((size_t)c*VC + l)*CEMB + h*HD + wq*8;
    const int ebase = wq*8*64 + (l & 7);
    const int el3   = l >> 3;
    // Ps write offsets per mt (b64): [q'=l15][v-octet mt*2+(quad>>1)], half quad&1
    int pgoff[4];
    #pragma unroll
    for (int mt = 0; mt < 4; ++mt)
        pgoff[mt] = (((mt*2 + (quad >> 1)) ^ X7) * 8) + (quad & 1)*4;

    // ---- prologue: stage subtile 0 into buffer 0 ----
    {
        float4 ka = *(const float4*)kgl, kb4 = *(const float4*)(kgl + 4);
        float4 ea = *(const float4*)egl, eb  = *(const float4*)(egl + 4);
        uint4 kw;
        kw.x = pk_trunc(ka.y,  ka.x);  kw.y = pk_trunc(ka.w,  ka.z);
        kw.z = pk_trunc(kb4.y, kb4.x); kw.w = pk_trunc(kb4.w, kb4.z);
        *(uint4*)&KB[0][kwidx] = kw;
        float ef8[8] = {ea.x, ea.y, ea.z, ea.w, eb.x, eb.y, eb.z, eb.w};
        #pragma unroll
        for (int j = 0; j < 8; ++j)
            ED[0][ebase + j*64 + ((el3 ^ j) * 8)] = hi16(ef8[j]);
        __syncthreads();
    }

    for (int s = 0; s < NSUB; ++s) {
        const int cur = s & 1, nxt = cur ^ 1;
        const bool pre = (s + 1 < NSUB);
        float4 ka, kb4, ea, eb;
        if (pre) {                             // prefetch next subtile (in flight all phase)
            const float* kp = kgl + (size_t)(s+1)*4096;
            ka = *(const float4*)kp; kb4 = *(const float4*)(kp + 4);
            const float* ep = egl + (size_t)(s+1)*(64*CEMB);
            ea = *(const float4*)ep; eb  = *(const float4*)(ep + 4);
        }

        // ---- preload K/E fragments (reused across all nt) ----
        v8bf kf0[4], kf1[4], ef0[4], ef1[4];
        #pragma unroll
        for (int mt = 0; mt < 4; ++mt) {
            kf0[mt] = *(const v8bf*)&KB[cur][mt*1024 + rowb + g0];
            kf1[mt] = *(const v8bf*)&KB[cur][mt*1024 + rowb + g1];
        }
        #pragma unroll
        for (int nd = 0; nd < 4; ++nd) {
            ef0[nd] = *(const v8bf*)&ED[cur][nd*1024 + rowb + g0];
            ef1[nd] = *(const v8bf*)&ED[cur][nd*1024 + rowb + g1];
        }

        #pragma unroll
        for (int nt = 0; nt < 4; ++nt) {
            // phase A: S^T = K.Q^T (log2 domain), p = exp2, truncate, store
            #pragma unroll
            for (int mt = 0; mt < 4; ++mt) {
                v4f sa = {0.f,0.f,0.f,0.f};
                sa = __builtin_amdgcn_mfma_f32_16x16x32_bf16(kf0[mt], qf[nt][0], sa, 0, 0, 0);
                sa = __builtin_amdgcn_mfma_f32_16x16x32_bf16(kf1[mt], qf[nt][1], sa, 0, 0, 0);
                float p0 = exp2f(sa[0]), p1 = exp2f(sa[1]);
                float p2 = exp2f(sa[2]), p3 = exp2f(sa[3]);
                // Z sums the truncated weights -> numerator/denominator consistent
                zacc[nt] += __uint_as_float(__float_as_uint(p0) & 0xffff0000u)
                          + __uint_as_float(__float_as_uint(p1) & 0xffff0000u)
                          + __uint_as_float(__float_as_uint(p2) & 0xffff0000u)
                          + __uint_as_float(__float_as_uint(p3) & 0xffff0000u);
                uint2 w = { pk_trunc(p1, p0), pk_trunc(p3, p2) };
                *(uint2*)&PS[rowb + pgoff[mt]] = w;
            }
            // phase B: O[nt-block] += P . E   (Ps wave-private, no barrier)
            v8bf pf0 = *(const v8bf*)&PS[rowb + g0];
            v8bf pf1 = *(const v8bf*)&PS[rowb + g1];
            #pragma unroll
            for (int nd = 0; nd < 4; ++nd) {
                o[nt][nd] = __builtin_amdgcn_mfma_f32_16x16x32_bf16(pf0, ef0[nd], o[nt][nd], 0, 0, 0);
                o[nt][nd] = __builtin_amdgcn_mfma_f32_16x16x32_bf16(pf1, ef1[nd], o[nt][nd], 0, 0, 0);
            }
        }

        if (pre) {                             // convert + write next buffers
            uint4 kw;
            kw.x = pk_trunc(ka.y,  ka.x);  kw.y = pk_trunc(ka.w,  ka.z);
            kw.z = pk_trunc(kb4.y, kb4.x); kw.w = pk_trunc(kb4.w, kb4.z);
            *(uint4*)&KB[nxt][kwidx] = kw;
            float ef8[8] = {ea.x, ea.y, ea.z, ea.w, eb.x, eb.y, eb.z, eb.w};
            #pragma unroll
            for (int j = 0; j < 8; ++j)
                ED[nxt][ebase + j*64 + ((el3 ^ j) * 8)] = hi16(ef8[j]);
            __syncthreads();                   // one barrier per subtile
        }
    }

    // ---- Z: quads hold disjoint v-partials -> butterfly over 16, 32 ----
    #pragma unroll
    for (int nt = 0; nt < 4; ++nt) {
        float z = zacc[nt];
        z += __shfl_xor(z, 16, 64);
        z += __shfl_xor(z, 32, 64);
        if (quad == 0)
            Zpart[((size_t)c*T_TOK + tbase + nt*16 + l15)*NH + h] = z;
    }
    // ---- store O[q][d] bf16: lane holds 4 q (quad*4+r) at fixed d ----
    #pragma unroll
    for (int nt = 0; nt < 4; ++nt) {
        #pragma unroll
        for (int nd = 0; nd < 4; ++nd) {
            v4f ov = o[nt][nd];
            #pragma unroll
            for (int r = 0; r < 4; ++r) {
                const int t = tbase + nt*16 + quad*4 + r;
                Npart[(((size_t)c*T_TOK + t)*NH + h)*HD + nd*16 + l15] = f2bf(ov[r]);
            }
        }
    }
}

// ---------------------------------------------------------------------------
// Kernel 3: out[t, h*64+d] = sum_c N[c,t,h,d] / sum_c Z[c,t,h]   (2 elems/thr)
// ---------------------------------------------------------------------------
__global__ void combine_kernel(const unsigned short* __restrict__ Npart,
                               const float* __restrict__ Zpart,
                               float* __restrict__ out) {
    const int idx = (blockIdx.x*256 + threadIdx.x)*2;
    const int t = idx / CEMB;
    const int rem = idx % CEMB;
    const int h = rem >> 6, d = rem & 63;
    float n0 = 0.f, n1 = 0.f, z = 0.f;
    #pragma unroll
    for (int c = 0; c < NC; ++c) {
        unsigned u = *(const unsigned*)&Npart[(((size_t)c*T_TOK + t)*NH + h)*HD + d];
        n0 += bf2f((unsigned short)(u & 0xffffu));
        n1 += bf2f((unsigned short)(u >> 16));
        z  += Zpart[((size_t)c*T_TOK + t)*NH + h];
    }
    out[idx]   = n0 / z;
    out[idx+1] = n1 / z;
}

extern "C" void kernel_launch(void* const* d_in, const int* in_sizes, int n_in,
                              void* d_out, int out_size, void* d_ws, size_t ws_size,
                              hipStream_t stream) {
    const float* x     = (const float*)d_in[0];
    const float* Wf    = (const float*)d_in[1];
    const float* bfv   = (const float*)d_in[2];
    const float* Wv    = (const float*)d_in[3];
    const float* temps = (const float*)d_in[4];
    const float* E     = (const float*)d_in[5];
    float* out = (float*)d_out;

    // workspace (bytes): Npart bf16 39,321,600 | Zpart f32 1,228,800 | Qb bf16 786,432
    char* ws = (char*)d_ws;
    unsigned short* Npart = (unsigned short*)ws;
    float*          Zpart = (float*)(ws + 39321600);
    unsigned short* Qb    = (unsigned short*)(ws + 40550400);

    ffn_kernel    <<<dim3(T_TOK/16, NH), 256, 0, stream>>>(x, Wf, bfv, temps, Qb);
    flash_mfma    <<<dim3(NC, NH),       512, 0, stream>>>(Qb, Wv, E, Npart, Zpart);
    combine_kernel<<<dim3((T_TOK*CEMB)/512), 256, 0, stream>>>(Npart, Zpart, out);
}